// Round 1
// 282.422 us; speedup vs baseline: 1.0161x; 1.0161x over previous
//
#include <hip/hip_runtime.h>
#include <hip/hip_bf16.h>
#include <cstdint>
#include <cstddef>

#define K_DIM 4096
#define NT 64            // K-tiles of 64

typedef __bf16 bf16x8 __attribute__((ext_vector_type(8)));
typedef float  f32x4  __attribute__((ext_vector_type(4)));
typedef unsigned short ushort8 __attribute__((ext_vector_type(8)));

struct KronPtrs { const float* a[8]; const float* b[8]; };

// ---------------------------------------------------------------------------
// Fused prologue (unchanged — write-bound, ~22 µs).
// ---------------------------------------------------------------------------
__global__ __launch_bounds__(256) void prologue_kernel(
        KronPtrs P,
        const float* __restrict__ x,
        __hip_bfloat16* __restrict__ Wb,
        __hip_bfloat16* __restrict__ Xb)
{
    __shared__ __align__(16) float sa[1080];
    __shared__ __align__(16) float sb[1080];

    const int tid = threadIdx.x;

    if (blockIdx.x < 8192) {
        const size_t t = (size_t)blockIdx.x * 256 + tid;
        const size_t o = t * 8;
        const float4 v0 = *(const float4*)(x + o);
        const float4 v1 = *(const float4*)(x + o + 4);
        union { __hip_bfloat16 h[8]; ushort8 v; } u;
        u.h[0] = __float2bfloat16(v0.x);
        u.h[1] = __float2bfloat16(v0.y);
        u.h[2] = __float2bfloat16(v0.z);
        u.h[3] = __float2bfloat16(v0.w);
        u.h[4] = __float2bfloat16(v1.x);
        u.h[5] = __float2bfloat16(v1.y);
        u.h[6] = __float2bfloat16(v1.z);
        u.h[7] = __float2bfloat16(v1.w);
        *(ushort8*)(void*)(Xb + o) = u.v;
        return;
    }

    const int row = blockIdx.x - 8192;

#define STAGE(IDX, MA, LB, OA, OB)                                             \
    {                                                                          \
        const int mb_ = 1 << (LB);                                             \
        const float* ap = P.a[IDX] + (size_t)(row >> (LB)) * (MA);             \
        const float* bp = P.b[IDX] + (size_t)(row & (mb_ - 1)) * mb_;          \
        for (int i = tid; i < (MA); i += 256) sa[(OA) + i] = ap[i];            \
        for (int i = tid; i < mb_;  i += 256) sb[(OB) + i] = bp[i];            \
    }

    STAGE(0,  64, 6,   0,    0)
    STAGE(1,  64, 6,  64,   64)
    STAGE(2,  32, 7, 128,  128)
    STAGE(3, 128, 5, 160,  256)
    STAGE(4,  16, 8, 288,  288)
    STAGE(5, 256, 4, 304,  544)
    STAGE(6,   8, 9, 560,  560)
    STAGE(7, 512, 3, 568, 1072)
#undef STAGE

    __syncthreads();

    const float s = 0.17677669529663687f;  // 1 / (2*sqrt(8))
    const int q0 = tid << 4;

#pragma unroll
    for (int g = 0; g < 2; ++g) {
        const int q8 = q0 + (g << 3);
        float acc[8] = {0.f,0.f,0.f,0.f,0.f,0.f,0.f,0.f};

#define KTERM(LB, OA, OB)                                                      \
    {                                                                          \
        const int mb_   = 1 << (LB);                                           \
        const float av  = sa[(OA) + (q8 >> (LB))];                             \
        const float* bp = sb + (OB) + (q8 & (mb_ - 1));                        \
        const float4 x0 = *(const float4*)(bp);                                \
        const float4 x1 = *(const float4*)(bp + 4);                            \
        acc[0] += av * x0.x; acc[1] += av * x0.y;                              \
        acc[2] += av * x0.z; acc[3] += av * x0.w;                              \
        acc[4] += av * x1.x; acc[5] += av * x1.y;                              \
        acc[6] += av * x1.z; acc[7] += av * x1.w;                              \
    }

        KTERM(6,   0,    0)
        KTERM(6,  64,   64)
        KTERM(7, 128,  128)
        KTERM(5, 160,  256)
        KTERM(8, 288,  288)
        KTERM(4, 304,  544)
        KTERM(9, 560,  560)
        KTERM(3, 568, 1072)
#undef KTERM

        union { __hip_bfloat16 h[8]; ushort8 v; } u;
#pragma unroll
        for (int i = 0; i < 8; ++i) u.h[i] = __float2bfloat16(acc[i] * s);
        *(ushort8*)(void*)(Wb + (size_t)row * K_DIM + q8) = u.v;
    }
}

// ---------------------------------------------------------------------------
// GEMM R5: 256x256 tile, 8-wave (2Mx4N), BK=64, 8-phase schedule with counted
// vmcnt(6) (m201 template). Each K-tile = 4 phases; per phase: ds-read one
// frag subtile + stage ONE 16KB half-tile (2x global_load_lds_dwordx4/thread)
// + barrier + 16 MFMA (one per-wave C-quadrant x K=64) + barrier. vmcnt(6)
// only once per K-tile -> 3 half-tiles stay in flight across barriers.
// A-frags cached across the two n-phases, B-frags across the two m-phases,
// so each LDS region's last ds_read is >=1 barrier before the stage that
// overwrites it (race-free; re-derived for this quadrant order).
// Staging swizzle (unchanged, measured 0 conflicts): within each 1KB chunk
// (8 rows x 128B), phys 16B-chunk p of row r holds logical chunk p ^ (r&7);
// achieved by pre-swizzling the per-lane GLOBAL address, LDS dest linear.
// ---------------------------------------------------------------------------
__device__ __forceinline__ void gload_lds16(const void* g, void* l)
{
    __builtin_amdgcn_global_load_lds((const __attribute__((address_space(1))) void*)g,
                                     (__attribute__((address_space(3))) void*)l,
                                     16, 0, 0);
}

__global__ __launch_bounds__(512) void gemm_kernel(
        const __hip_bfloat16* __restrict__ Wb,
        const __hip_bfloat16* __restrict__ Xb,
        const float* __restrict__ bias,
        float* __restrict__ C)
{
    // [buf*2 + half][128 rows * 64 cols] ; A half h = tile rows h*128..h*128+127
    __shared__ __align__(16) __hip_bfloat16 lsA[4][8192];   // 64 KiB
    __shared__ __align__(16) __hip_bfloat16 lsB[4][8192];   // 64 KiB

    const int tid  = threadIdx.x;
    const int lane = tid & 63;
    const int wid  = tid >> 6;    // 0..7
    const int wr   = wid >> 2;    // 0..1 (M)
    const int wc   = wid & 3;     // 0..3 (N)

    // XCD-aware bijective swizzle of the 256-block grid (16x16 tiles).
    const int bid = blockIdx.x;
    const int lin = (bid & 7) * 32 + (bid >> 3);
    const int bm  = (lin >> 4) << 8;
    const int bn  = (lin & 15) << 8;

    // --- staging source pointers (pre-swizzled global addresses) ---
    const int sr = lane >> 3;            // row within 8-row chunk
    const int lc = (lane & 7) ^ sr;      // logical 16B chunk to fetch
    const __hip_bfloat16* gA[2][2];
    const __hip_bfloat16* gB[2][2];
#pragma unroll
    for (int h = 0; h < 2; ++h)
#pragma unroll
        for (int r = 0; r < 2; ++r) {
            const int rowo = h * 128 + (wid + 8 * r) * 8 + sr;
            gA[h][r] = Wb + (size_t)(bm + rowo) * K_DIM + lc * 8;
            gB[h][r] = Xb + (size_t)(bn + rowo) * K_DIM + lc * 8;
        }

    // --- accumulators: per-wave 128x64 output, quadrants [m][n], frags [mi][ni]
    f32x4 acc[2][2][4][2];
#pragma unroll
    for (int m = 0; m < 2; ++m)
#pragma unroll
        for (int n = 0; n < 2; ++n)
#pragma unroll
            for (int mi = 0; mi < 4; ++mi)
#pragma unroll
                for (int ni = 0; ni < 2; ++ni) acc[m][n][mi][ni] = (f32x4)(0.0f);

    bf16x8 af[2][4];      // current m-half A frags [kk][mi]
    bf16x8 bf[2][2][2];   // both n-half B frags  [n][kk][ni]

    const int fr = lane & 15;   // frag row
    const int fq = lane >> 4;   // quad
    const int fx = fr & 7;      // read-side swizzle xor

    // LDS read bases (p=0 buffer; p=1 via +16384-elem immediate).
    const int e0 = ((0 * 4 + fq) ^ fx) << 3;            // kk=0 chunk, elements
    const int dK = (fx & 4) ? -32 : 32;                 // kk=1 chunk delta (elems)
    const __hip_bfloat16* aPtr[2];
    const __hip_bfloat16* bPtr[2];
    aPtr[0] = &lsA[0][0] + ((wr << 6) + fr) * 64 + e0;
    aPtr[1] = &lsA[1][0] + ((wr << 6) + fr) * 64 + e0;
    bPtr[0] = &lsB[0][0] + ((wc << 5) + fr) * 64 + e0;
    bPtr[1] = &lsB[1][0] + ((wc << 5) + fr) * 64 + e0;

#define STAGE_A(h, p) do {                                                     \
    gload_lds16(gA[h][0], &lsA[(p)*2 + (h)][wid << 9]);       gA[h][0] += 64;  \
    gload_lds16(gA[h][1], &lsA[(p)*2 + (h)][(wid + 8) << 9]); gA[h][1] += 64;  \
} while (0)

#define STAGE_B(h, p) do {                                                     \
    gload_lds16(gB[h][0], &lsB[(p)*2 + (h)][wid << 9]);       gB[h][0] += 64;  \
    gload_lds16(gB[h][1], &lsB[(p)*2 + (h)][(wid + 8) << 9]); gB[h][1] += 64;  \
} while (0)

#define LOAD_A(p, h) do {                                                      \
    const __hip_bfloat16* _pa = aPtr[h] + (p) * 16384;                         \
    af[0][0] = *(const bf16x8*)(const void*)(_pa);                             \
    af[0][1] = *(const bf16x8*)(const void*)(_pa + 1024);                      \
    af[0][2] = *(const bf16x8*)(const void*)(_pa + 2048);                      \
    af[0][3] = *(const bf16x8*)(const void*)(_pa + 3072);                      \
    af[1][0] = *(const bf16x8*)(const void*)(_pa + dK);                        \
    af[1][1] = *(const bf16x8*)(const void*)(_pa + dK + 1024);                 \
    af[1][2] = *(const bf16x8*)(const void*)(_pa + dK + 2048);                 \
    af[1][3] = *(const bf16x8*)(const void*)(_pa + dK + 3072);                 \
} while (0)

#define LOAD_B(p, h) do {                                                      \
    const __hip_bfloat16* _pb = bPtr[h] + (p) * 16384;                         \
    bf[h][0][0] = *(const bf16x8*)(const void*)(_pb);                          \
    bf[h][0][1] = *(const bf16x8*)(const void*)(_pb + 1024);                   \
    bf[h][1][0] = *(const bf16x8*)(const void*)(_pb + dK);                     \
    bf[h][1][1] = *(const bf16x8*)(const void*)(_pb + dK + 1024);              \
} while (0)

#define MMA(m, n) do {                                                         \
    __builtin_amdgcn_s_setprio(1);                                             \
    _Pragma("unroll") for (int kk = 0; kk < 2; ++kk)                           \
    _Pragma("unroll") for (int mi = 0; mi < 4; ++mi)                           \
    _Pragma("unroll") for (int ni = 0; ni < 2; ++ni)                           \
        acc[m][n][mi][ni] = __builtin_amdgcn_mfma_f32_16x16x32_bf16(           \
            af[kk][mi], bf[n][kk][ni], acc[m][n][mi][ni], 0, 0, 0);            \
    __builtin_amdgcn_s_setprio(0);                                             \
} while (0)

#define BAR()       __builtin_amdgcn_s_barrier()
#define WAIT_LGKM() asm volatile("s_waitcnt lgkmcnt(0)" ::: "memory")
#define WAIT_VM(N)  asm volatile("s_waitcnt vmcnt(" #N ")" ::: "memory")

    // One K-tile = 4 phases. Stage rotation: ph0 -> A1(t+1) (other buffer),
    // ph1 -> A0(t+2), ph2 -> B0(t+2), ph3 -> B1(t+2) (same buffer; each region's
    // last ds_read was >=1 barrier earlier thanks to frag caching).
#define TILE(p, SA1, SA0, SB0, SB1, VM) do {                                   \
    LOAD_A(p, 0); LOAD_B(p, 0); SA1;                                           \
    BAR(); WAIT_LGKM(); MMA(0, 0); BAR();                                      \
    LOAD_B(p, 1); SA0;                                                         \
    BAR(); WAIT_LGKM(); MMA(0, 1); BAR();                                      \
    LOAD_A(p, 1); SB0;                                                         \
    BAR(); WAIT_LGKM(); MMA(1, 0); BAR();                                      \
    SB1; VM;                                                                   \
    BAR(); MMA(1, 1); BAR();                                                   \
} while (0)

    // Prologue: tile0 fully + 3 half-tiles of tile1; vmcnt(6) confirms tile0.
    STAGE_A(0, 0); STAGE_B(0, 0); STAGE_B(1, 0); STAGE_A(1, 0);
    STAGE_A(0, 1); STAGE_B(0, 1); STAGE_B(1, 1);
    WAIT_VM(6);
    BAR();

    // Main loop: tiles 0..61 (31 iterations x 2 tiles, steady vmcnt(6)).
    for (int it = 0; it < 31; ++it) {
        TILE(0, STAGE_A(1, 1), STAGE_A(0, 0), STAGE_B(0, 0), STAGE_B(1, 0), WAIT_VM(6));
        TILE(1, STAGE_A(1, 0), STAGE_A(0, 1), STAGE_B(0, 1), STAGE_B(1, 1), WAIT_VM(6));
    }
    // Tile 62: stage only A1(63); drain at its boundary.
    TILE(0, STAGE_A(1, 1), (void)0, (void)0, (void)0, WAIT_VM(0));
    // Tile 63: pure compute.
    TILE(1, (void)0, (void)0, (void)0, (void)0, (void)0);

#undef TILE
#undef WAIT_VM
#undef WAIT_LGKM
#undef BAR
#undef MMA
#undef LOAD_B
#undef LOAD_A
#undef STAGE_B
#undef STAGE_A

    // Epilogue: C/D layout col = lane&15, row = (lane>>4)*4 + reg.
#pragma unroll
    for (int n = 0; n < 2; ++n)
#pragma unroll
        for (int ni = 0; ni < 2; ++ni) {
            const int col = bn + n * 128 + (wc << 5) + (ni << 4) + fr;
            const float bv = bias[col];
#pragma unroll
            for (int m = 0; m < 2; ++m)
#pragma unroll
                for (int mi = 0; mi < 4; ++mi) {
                    const int r0 = bm + m * 128 + (wr << 6) + (mi << 4) + (fq << 2);
#pragma unroll
                    for (int i = 0; i < 4; ++i)
                        C[(size_t)(r0 + i) * K_DIM + col] = acc[m][n][mi][ni][i] + bv;
                }
        }
}

// ---------------------------------------------------------------------------
extern "C" void kernel_launch(void* const* d_in, const int* in_sizes, int n_in,
                              void* d_out, int out_size, void* d_ws, size_t ws_size,
                              hipStream_t stream)
{
    (void)in_sizes; (void)n_in; (void)out_size; (void)ws_size;

    const float* x    = (const float*)d_in[0];
    KronPtrs P;
    for (int i = 0; i < 8; ++i) {
        P.a[i] = (const float*)d_in[1 + i];
        P.b[i] = (const float*)d_in[9 + i];
    }
    const float* bias = (const float*)d_in[17];

    __hip_bfloat16* Wb = (__hip_bfloat16*)d_ws;                               // 32 MiB
    __hip_bfloat16* Xb = (__hip_bfloat16*)((char*)d_ws +
                          (size_t)K_DIM * K_DIM * sizeof(__hip_bfloat16));    // 32 MiB
    float* y = (float*)d_out;

    prologue_kernel<<<12288, 256, 0, stream>>>(P, x, Wb, Xb);

    gemm_kernel<<<256, 512, 0, stream>>>(Wb, Xb, bias, y);
}